// Round 1
// baseline (658.443 us; speedup 1.0000x reference)
//
#include <hip/hip_runtime.h>
#include <math.h>

#define N_NODES 10000
#define N_EDGES 160000
#define D 512

// ---------------------------------------------------------------- utilities

__global__ void zero_int_kernel(int* __restrict__ p, int n) {
    int i = blockIdx.x * blockDim.x + threadIdx.x;
    if (i < n) p[i] = 0;
}

// count in-degree (dst occurrences). edge_index layout [2,E] row-major:
// src = ei[e], dst = ei[E+e]
__global__ void deg_kernel(const int* __restrict__ ei, int* __restrict__ cnt) {
    int e = blockIdx.x * blockDim.x + threadIdx.x;
    if (e < N_EDGES) atomicAdd(&cnt[ei[N_EDGES + e]], 1);
}

__global__ void dinv_kernel(const int* __restrict__ cnt, float* __restrict__ dinv) {
    int i = blockIdx.x * blockDim.x + threadIdx.x;
    if (i < N_NODES) dinv[i] = rsqrtf((float)cnt[i] + 1.0f);
}

// exclusive prefix sum of cnt[0..N) -> rowp[0..N], single block of 1024
__global__ __launch_bounds__(1024) void scan_kernel(const int* __restrict__ cnt,
                                                    int* __restrict__ rowp) {
    __shared__ int sm[1024];
    __shared__ int carry;
    if (threadIdx.x == 0) carry = 0;
    __syncthreads();
    for (int base = 0; base < N_NODES; base += 1024) {
        int i = base + threadIdx.x;
        int v = (i < N_NODES) ? cnt[i] : 0;
        sm[threadIdx.x] = v;
        __syncthreads();
        for (int off = 1; off < 1024; off <<= 1) {
            int t = (threadIdx.x >= off) ? sm[threadIdx.x - off] : 0;
            __syncthreads();
            sm[threadIdx.x] += t;
            __syncthreads();
        }
        int incl = sm[threadIdx.x] + carry;
        if (i < N_NODES) rowp[i + 1] = incl;
        __syncthreads();
        if (threadIdx.x == 1023) carry = incl;
        __syncthreads();
    }
    if (threadIdx.x == 0) rowp[0] = 0;
}

__global__ void copy_int_kernel(const int* __restrict__ src, int* __restrict__ dst, int n) {
    int i = blockIdx.x * blockDim.x + threadIdx.x;
    if (i < n) dst[i] = src[i];
}

// scatter edges into CSR (by dst): esrc[pos]=src, ecoef[pos]=dinv[src]*dinv[dst]
__global__ void fill_kernel(const int* __restrict__ ei, const float* __restrict__ dinv,
                            int* __restrict__ fillpos, int* __restrict__ esrc,
                            float* __restrict__ ecoef) {
    int e = blockIdx.x * blockDim.x + threadIdx.x;
    if (e >= N_EDGES) return;
    int s = ei[e], d = ei[N_EDGES + e];
    int pos = atomicAdd(&fillpos[d], 1);
    esrc[pos] = s;
    ecoef[pos] = dinv[s] * dinv[d];
}

// out[i,j] = x[i,j] + cos(t[i]*w[j] + b[j])
__global__ void te_kernel(const float* __restrict__ x, const float* __restrict__ t,
                          const float* __restrict__ w, const float* __restrict__ b,
                          float* __restrict__ out) {
    int idx = blockIdx.x * blockDim.x + threadIdx.x;
    if (idx >= N_NODES * D) return;
    int i = idx >> 9;
    int j = idx & (D - 1);
    out[idx] = x[idx] + cosf(t[i] * w[j] + b[j]);
}

// ---------------------------------------------------------------- fp32 GEMM
// C[M,512] = A[M,512] @ B[512,512], all row-major. 64x64 tile, BK=16,
// 256 threads, 4x4 microtile.
#define BM 64
#define BN 64
#define BK 16

__global__ __launch_bounds__(256) void gemm_kernel(const float* __restrict__ A,
                                                   const float* __restrict__ B,
                                                   float* __restrict__ C, int M) {
    __shared__ float As[BK][BM + 1];
    __shared__ float Bs[BK][BN];
    const int bm = blockIdx.y * BM;
    const int bn = blockIdx.x * BN;
    const int tid = threadIdx.x;
    const int tx = tid & 15;   // -> n
    const int ty = tid >> 4;   // -> m
    float acc[4][4] = {};

    for (int k0 = 0; k0 < D; k0 += BK) {
        // A tile: 64 rows x 16 k; each thread: one float4 along k
        {
            int r = tid >> 2;          // 0..63
            int c4 = (tid & 3) * 4;    // 0,4,8,12
            int gr = bm + r;
            float4 v = (gr < M) ? *(const float4*)&A[gr * D + k0 + c4]
                                : make_float4(0.f, 0.f, 0.f, 0.f);
            As[c4 + 0][r] = v.x;
            As[c4 + 1][r] = v.y;
            As[c4 + 2][r] = v.z;
            As[c4 + 3][r] = v.w;
        }
        // B tile: 16 k x 64 n; each thread: one float4 along n
        {
            int r = tid >> 4;          // 0..15
            int c4 = (tid & 15) * 4;   // 0..60
            float4 v = *(const float4*)&B[(k0 + r) * D + bn + c4];
            *(float4*)&Bs[r][c4] = v;
        }
        __syncthreads();
#pragma unroll
        for (int kk = 0; kk < BK; ++kk) {
            float a[4], bb[4];
#pragma unroll
            for (int i = 0; i < 4; ++i) a[i] = As[kk][ty * 4 + i];
#pragma unroll
            for (int i = 0; i < 4; ++i) bb[i] = Bs[kk][tx * 4 + i];
#pragma unroll
            for (int i = 0; i < 4; ++i)
#pragma unroll
                for (int j = 0; j < 4; ++j) acc[i][j] += a[i] * bb[j];
        }
        __syncthreads();
    }
#pragma unroll
    for (int i = 0; i < 4; ++i) {
        int gr = bm + ty * 4 + i;
        if (gr < M) {
            float4 v = make_float4(acc[i][0], acc[i][1], acc[i][2], acc[i][3]);
            *(float4*)&C[gr * D + bn + tx * 4] = v;
        }
    }
}

// ---------------------------------------------------------------- aggregate
// out[i,:] = sum_{e in CSR[i]} coef_e * h[src_e,:] + dinv[i]^2 * h[i,:] + bias
// one block (256 threads) per node; thread covers features f and f+256
__global__ __launch_bounds__(256) void aggregate_kernel(
    const float* __restrict__ h, const int* __restrict__ rowp,
    const int* __restrict__ esrc, const float* __restrict__ ecoef,
    const float* __restrict__ dinv, const float* __restrict__ bias,
    float* __restrict__ out) {
    int node = blockIdx.x;
    int f = threadIdx.x;
    float acc0 = 0.f, acc1 = 0.f;
    int beg = rowp[node], end = rowp[node + 1];
    for (int e = beg; e < end; ++e) {
        int s = esrc[e];
        float c = ecoef[e];
        acc0 += h[s * D + f] * c;
        acc1 += h[s * D + f + 256] * c;
    }
    float dv = dinv[node];
    float self = dv * dv;
    acc0 += h[node * D + f] * self + bias[f];
    acc1 += h[node * D + f + 256] * self + bias[f + 256];
    out[node * D + f] = acc0;
    out[node * D + f + 256] = acc1;
}

// ---------------------------------------------------------------- classifier
// phase 0: z[i,c]  = sum_j h[i,j]*fcw[j*2+c]
// phase 1: z[i,c] += sum_j h[i,j]*fcw[(512+j)*2+c]; add fcb; log_softmax -> out
__global__ __launch_bounds__(256) void final_kernel(const float* __restrict__ h,
                                                    const float* __restrict__ fcw,
                                                    const float* __restrict__ fcb,
                                                    float* __restrict__ z,
                                                    float* __restrict__ out, int phase) {
    int node = blockIdx.x * (blockDim.x >> 6) + (threadIdx.x >> 6);
    int lane = threadIdx.x & 63;
    if (node >= N_NODES) return;
    const float* w = fcw + (phase ? (D * 2) : 0);
    float z0 = 0.f, z1 = 0.f;
    for (int j = lane; j < D; j += 64) {
        float a = h[node * D + j];
        z0 += a * w[j * 2 + 0];
        z1 += a * w[j * 2 + 1];
    }
#pragma unroll
    for (int off = 32; off; off >>= 1) {
        z0 += __shfl_down(z0, off);
        z1 += __shfl_down(z1, off);
    }
    if (lane == 0) {
        if (phase == 0) {
            z[node * 2 + 0] = z0;
            z[node * 2 + 1] = z1;
        } else {
            z0 += z[node * 2 + 0] + fcb[0];
            z1 += z[node * 2 + 1] + fcb[1];
            float m = fmaxf(z0, z1);
            float l = m + logf(expf(z0 - m) + expf(z1 - m));
            out[node * 2 + 0] = z0 - l;
            out[node * 2 + 1] = z1 - l;
        }
    }
}

// ---------------------------------------------------------------- launch

extern "C" void kernel_launch(void* const* d_in, const int* in_sizes, int n_in,
                              void* d_out, int out_size, void* d_ws, size_t ws_size,
                              hipStream_t stream) {
    const float* x        = (const float*)d_in[0];
    const int*   ein      = (const int*)d_in[1];
    const int*   eout     = (const int*)d_in[2];
    const float* t        = (const float*)d_in[3];
    const float* te_w_in  = (const float*)d_in[4];
    const float* te_b_in  = (const float*)d_in[5];
    const float* W1_in    = (const float*)d_in[6];
    const float* b1_in    = (const float*)d_in[7];
    const float* W2_in    = (const float*)d_in[8];
    const float* b2_in    = (const float*)d_in[9];
    const float* te_w_out = (const float*)d_in[10];
    const float* te_b_out = (const float*)d_in[11];
    const float* W1_out   = (const float*)d_in[12];
    const float* b1_out   = (const float*)d_in[13];
    const float* W2_out   = (const float*)d_in[14];
    const float* b2_out   = (const float*)d_in[15];
    const float* fc_w     = (const float*)d_in[16];
    const float* fc_b     = (const float*)d_in[17];
    float* out = (float*)d_out;

    // ---- workspace carve (all buffers fully written before read each call)
    char* p = (char*)d_ws;
    auto carve = [&](size_t bytes) {
        void* r = (void*)p;
        p += ((bytes + 255) / 256) * 256;
        return r;
    };
    float* buf0 = (float*)carve((size_t)N_NODES * D * 4);
    float* buf1 = (float*)carve((size_t)N_NODES * D * 4);
    float* z    = (float*)carve((size_t)N_NODES * 2 * 4);
    int*   cnt[2];   cnt[0]   = (int*)carve(N_NODES * 4);     cnt[1]   = (int*)carve(N_NODES * 4);
    float* dinv[2];  dinv[0]  = (float*)carve(N_NODES * 4);   dinv[1]  = (float*)carve(N_NODES * 4);
    int*   rowp[2];  rowp[0]  = (int*)carve((N_NODES + 1) * 4); rowp[1] = (int*)carve((N_NODES + 1) * 4);
    int*   fillpos  = (int*)carve(N_NODES * 4);
    int*   esrc[2];  esrc[0]  = (int*)carve(N_EDGES * 4);     esrc[1]  = (int*)carve(N_EDGES * 4);
    float* ecoef[2]; ecoef[0] = (float*)carve(N_EDGES * 4);   ecoef[1] = (float*)carve(N_EDGES * 4);

    const int* edges[2] = {ein, eout};

    // ---- build degree + CSR for both branches
    int gridE = (N_EDGES + 255) / 256;
    int gridN = (N_NODES + 255) / 256;
    for (int b = 0; b < 2; ++b) {
        zero_int_kernel<<<gridN, 256, 0, stream>>>(cnt[b], N_NODES);
        deg_kernel<<<gridE, 256, 0, stream>>>(edges[b], cnt[b]);
        dinv_kernel<<<gridN, 256, 0, stream>>>(cnt[b], dinv[b]);
        scan_kernel<<<1, 1024, 0, stream>>>(cnt[b], rowp[b]);
        copy_int_kernel<<<gridN, 256, 0, stream>>>(rowp[b], fillpos, N_NODES);
        fill_kernel<<<gridE, 256, 0, stream>>>(edges[b], dinv[b], fillpos, esrc[b], ecoef[b]);
    }

    // ---- two branches
    const float* te_w[2] = {te_w_in, te_w_out};
    const float* te_b[2] = {te_b_in, te_b_out};
    const float* W1[2]   = {W1_in, W1_out};
    const float* b1[2]   = {b1_in, b1_out};
    const float* W2[2]   = {W2_in, W2_out};
    const float* b2[2]   = {b2_in, b2_out};

    dim3 gemm_grid(D / BN, (N_NODES + BM - 1) / BM);
    int te_grid = (N_NODES * D + 255) / 256;
    int fin_grid = (N_NODES + 3) / 4;

    for (int b = 0; b < 2; ++b) {
        te_kernel<<<te_grid, 256, 0, stream>>>(x, t, te_w[b], te_b[b], buf0);
        gemm_kernel<<<gemm_grid, 256, 0, stream>>>(buf0, W1[b], buf1, N_NODES);
        aggregate_kernel<<<N_NODES, 256, 0, stream>>>(buf1, rowp[b], esrc[b], ecoef[b],
                                                      dinv[b], b1[b], buf0);
        gemm_kernel<<<gemm_grid, 256, 0, stream>>>(buf0, W2[b], buf1, N_NODES);
        aggregate_kernel<<<N_NODES, 256, 0, stream>>>(buf1, rowp[b], esrc[b], ecoef[b],
                                                      dinv[b], b2[b], buf0);
        final_kernel<<<fin_grid, 256, 0, stream>>>(buf0, fc_w, fc_b, z, out, b);
    }
}

// Round 2
// 452.762 us; speedup vs baseline: 1.4543x; 1.4543x over previous
//
#include <hip/hip_runtime.h>
#include <hip/hip_bf16.h>
#include <math.h>

#define N_NODES 10000
#define N_EDGES 160000
#define D 512

typedef __attribute__((ext_vector_type(8))) short bf16x8;
typedef __attribute__((ext_vector_type(4))) float f32x4;

__device__ inline void gload_lds16(const void* g, void* l) {
    __builtin_amdgcn_global_load_lds(
        (const __attribute__((address_space(1))) void*)g,
        (__attribute__((address_space(3))) void*)l, 16, 0, 0);
}

// ---------------------------------------------------------------- utilities

__global__ void zero_int_kernel(int* __restrict__ p, int n) {
    int i = blockIdx.x * blockDim.x + threadIdx.x;
    if (i < n) p[i] = 0;
}

__global__ void deg_kernel(const int* __restrict__ ei, int* __restrict__ cnt) {
    int e = blockIdx.x * blockDim.x + threadIdx.x;
    if (e < N_EDGES) atomicAdd(&cnt[ei[N_EDGES + e]], 1);
}

__global__ void dinv_kernel(const int* __restrict__ cnt, float* __restrict__ dinv) {
    int i = blockIdx.x * blockDim.x + threadIdx.x;
    if (i < N_NODES) dinv[i] = rsqrtf((float)cnt[i] + 1.0f);
}

__global__ __launch_bounds__(1024) void scan_kernel(const int* __restrict__ cnt,
                                                    int* __restrict__ rowp) {
    __shared__ int sm[1024];
    __shared__ int carry;
    if (threadIdx.x == 0) carry = 0;
    __syncthreads();
    for (int base = 0; base < N_NODES; base += 1024) {
        int i = base + threadIdx.x;
        int v = (i < N_NODES) ? cnt[i] : 0;
        sm[threadIdx.x] = v;
        __syncthreads();
        for (int off = 1; off < 1024; off <<= 1) {
            int t = (threadIdx.x >= off) ? sm[threadIdx.x - off] : 0;
            __syncthreads();
            sm[threadIdx.x] += t;
            __syncthreads();
        }
        int incl = sm[threadIdx.x] + carry;
        if (i < N_NODES) rowp[i + 1] = incl;
        __syncthreads();
        if (threadIdx.x == 1023) carry = incl;
        __syncthreads();
    }
    if (threadIdx.x == 0) rowp[0] = 0;
}

__global__ void copy_int_kernel(const int* __restrict__ src, int* __restrict__ dst, int n) {
    int i = blockIdx.x * blockDim.x + threadIdx.x;
    if (i < n) dst[i] = src[i];
}

__global__ void fill_kernel(const int* __restrict__ ei, const float* __restrict__ dinv,
                            int* __restrict__ fillpos, int* __restrict__ esrc,
                            float* __restrict__ ecoef) {
    int e = blockIdx.x * blockDim.x + threadIdx.x;
    if (e >= N_EDGES) return;
    int s = ei[e], d = ei[N_EDGES + e];
    int pos = atomicAdd(&fillpos[d], 1);
    esrc[pos] = s;
    ecoef[pos] = dinv[s] * dinv[d];
}

// ------------------------------------------------------------ split writers
// As layout: [i][0..511]=hi, [i][512..1023]=lo   (bf16, row stride 1024)

__global__ void te_split_kernel(const float* __restrict__ x, const float* __restrict__ t,
                                const float* __restrict__ w, const float* __restrict__ b,
                                __hip_bfloat16* __restrict__ As) {
    int idx = blockIdx.x * blockDim.x + threadIdx.x;
    if (idx >= N_NODES * D) return;
    int i = idx >> 9, j = idx & 511;
    float v = x[idx] + cosf(t[i] * w[j] + b[j]);
    __hip_bfloat16 h = __float2bfloat16(v);
    float lo = v - __bfloat162float(h);
    As[(size_t)i * 1024 + j] = h;
    As[(size_t)i * 1024 + 512 + j] = __float2bfloat16(lo);
}

// W is [K=512][N=512] row-major; Bt output is [n][0..511]=hi(W[k][n]), [n][512..1023]=lo
__global__ void split_w_kernel(const float* __restrict__ W, __hip_bfloat16* __restrict__ Bt) {
    int idx = blockIdx.x * blockDim.x + threadIdx.x;
    if (idx >= D * D) return;
    int n = idx >> 9, k = idx & 511;
    float v = W[k * D + n];
    __hip_bfloat16 h = __float2bfloat16(v);
    float lo = v - __bfloat162float(h);
    Bt[(size_t)n * 1024 + k] = h;
    Bt[(size_t)n * 1024 + 512 + k] = __float2bfloat16(lo);
}

// ---------------------------------------------------------------- MFMA GEMM
// C[M,512] = A(split)[M,1024] x Bt(split)[512,1024]^T  with 3-term hi/lo:
// K' = 1536: t<8: hi*hi; 8<=t<16: lo*hi; t>=16: hi*lo. 128x128 tile, BK=64.
// LDS rows are 128 B, XOR-swizzled: phys_slot = slot ^ (row & 7)  (16B slots).

__global__ __launch_bounds__(256) void gemm_mfma_kernel(
    const __hip_bfloat16* __restrict__ A, const __hip_bfloat16* __restrict__ Bt,
    float* __restrict__ C, int M) {
    __shared__ __align__(16) char lds[2][32768];  // [buf][A 16KB | B 16KB]
    const int tid = threadIdx.x;
    const int l = tid & 63;
    const int wid = tid >> 6;
    const int wm = wid >> 1, wn = wid & 1;
    const int bm = blockIdx.y * 128;
    const int bn = blockIdx.x * 128;

    f32x4 acc[4][4] = {};

    const int rl8 = l >> 3;            // row within 8-row group
    const int sslot = (l & 7) ^ rl8;   // pre-swizzled source slot

    auto stage = [&](int cur, int t) {
        int aoff, boff;
        if (t < 8)       { aoff = t * 64;             boff = t * 64; }
        else if (t < 16) { aoff = 512 + (t - 8) * 64; boff = (t - 8) * 64; }
        else             { aoff = (t - 16) * 64;      boff = 512 + (t - 16) * 64; }
        char* base = lds[cur];
#pragma unroll
        for (int j = 0; j < 4; ++j) {
            int rowl = (j * 4 + wid) * 8 + rl8;
            int grow = bm + rowl;
            if (grow > M - 1) grow = M - 1;
            gload_lds16(A + (size_t)grow * 1024 + aoff + sslot * 8,
                        base + (j * 4 + wid) * 1024);
        }
#pragma unroll
        for (int j = 0; j < 4; ++j) {
            int rowl = (j * 4 + wid) * 8 + rl8;
            gload_lds16(Bt + (size_t)(bn + rowl) * 1024 + boff + sslot * 8,
                        base + 16384 + (j * 4 + wid) * 1024);
        }
    };

    auto compute = [&](int cur) {
        const char* base = lds[cur];
        const char* baseB = base + 16384;
        const int ra = wm * 64 + (l & 15);
        const int rb = wn * 64 + (l & 15);
#pragma unroll
        for (int kk = 0; kk < 2; ++kk) {
            int slot = kk * 4 + (l >> 4);
            bf16x8 af[4], bfr[4];
#pragma unroll
            for (int m = 0; m < 4; ++m) {
                int row = ra + m * 16;
                af[m] = *(const bf16x8*)(base + row * 128 + ((slot ^ (row & 7)) * 16));
            }
#pragma unroll
            for (int n = 0; n < 4; ++n) {
                int row = rb + n * 16;
                bfr[n] = *(const bf16x8*)(baseB + row * 128 + ((slot ^ (row & 7)) * 16));
            }
#pragma unroll
            for (int m = 0; m < 4; ++m)
#pragma unroll
                for (int n = 0; n < 4; ++n)
                    acc[m][n] = __builtin_amdgcn_mfma_f32_16x16x32_bf16(
                        af[m], bfr[n], acc[m][n], 0, 0, 0);
        }
    };

    stage(0, 0);
    __syncthreads();
    int cur = 0;
#pragma unroll 1
    for (int t = 0; t < 24; ++t) {
        if (t < 23) stage(cur ^ 1, t + 1);
        compute(cur);
        __syncthreads();
        cur ^= 1;
    }

    const int col0 = bn + wn * 64 + (l & 15);
    const int row0 = bm + wm * 64 + (l >> 4) * 4;
#pragma unroll
    for (int m = 0; m < 4; ++m)
#pragma unroll
        for (int n = 0; n < 4; ++n)
#pragma unroll
            for (int r = 0; r < 4; ++r) {
                int row = row0 + m * 16 + r;
                if (row < M) C[(size_t)row * 512 + col0 + n * 16] = acc[m][n][r];
            }
}

// ---------------------------------------------------------------- aggregate
// out[i,:] = sum_e coef_e * h[src_e,:] + dinv[i]^2 * h[i,:] + bias
// SPLIT=1: write bf16 hi/lo [i][1024]; SPLIT=0: write fp32 [i][512]
template <int SPLIT>
__global__ __launch_bounds__(256) void aggregate_kernel(
    const float* __restrict__ h, const int* __restrict__ rowp,
    const int* __restrict__ esrc, const float* __restrict__ ecoef,
    const float* __restrict__ dinv, const float* __restrict__ bias,
    float* __restrict__ outf, __hip_bfloat16* __restrict__ outs) {
    int node = blockIdx.x;
    int f = threadIdx.x;
    float acc0 = 0.f, acc1 = 0.f;
    int beg = rowp[node], end = rowp[node + 1];
    for (int e = beg; e < end; ++e) {
        int s = esrc[e];
        float c = ecoef[e];
        acc0 += h[(size_t)s * D + f] * c;
        acc1 += h[(size_t)s * D + f + 256] * c;
    }
    float dv = dinv[node];
    float self = dv * dv;
    acc0 += h[(size_t)node * D + f] * self + bias[f];
    acc1 += h[(size_t)node * D + f + 256] * self + bias[f + 256];
    if (SPLIT) {
        __hip_bfloat16 h0 = __float2bfloat16(acc0);
        __hip_bfloat16 h1 = __float2bfloat16(acc1);
        outs[(size_t)node * 1024 + f] = h0;
        outs[(size_t)node * 1024 + 512 + f] = __float2bfloat16(acc0 - __bfloat162float(h0));
        outs[(size_t)node * 1024 + f + 256] = h1;
        outs[(size_t)node * 1024 + 512 + f + 256] = __float2bfloat16(acc1 - __bfloat162float(h1));
    } else {
        outf[(size_t)node * D + f] = acc0;
        outf[(size_t)node * D + f + 256] = acc1;
    }
}

// ---------------------------------------------------------------- classifier

__global__ __launch_bounds__(256) void final_kernel(const float* __restrict__ h,
                                                    const float* __restrict__ fcw,
                                                    const float* __restrict__ fcb,
                                                    float* __restrict__ z,
                                                    float* __restrict__ out, int phase) {
    int node = blockIdx.x * (blockDim.x >> 6) + (threadIdx.x >> 6);
    int lane = threadIdx.x & 63;
    if (node >= N_NODES) return;
    const float* w = fcw + (phase ? (D * 2) : 0);
    float z0 = 0.f, z1 = 0.f;
    for (int j = lane; j < D; j += 64) {
        float a = h[(size_t)node * D + j];
        z0 += a * w[j * 2 + 0];
        z1 += a * w[j * 2 + 1];
    }
#pragma unroll
    for (int off = 32; off; off >>= 1) {
        z0 += __shfl_down(z0, off);
        z1 += __shfl_down(z1, off);
    }
    if (lane == 0) {
        if (phase == 0) {
            z[node * 2 + 0] = z0;
            z[node * 2 + 1] = z1;
        } else {
            z0 += z[node * 2 + 0] + fcb[0];
            z1 += z[node * 2 + 1] + fcb[1];
            float m = fmaxf(z0, z1);
            float l2 = m + logf(expf(z0 - m) + expf(z1 - m));
            out[node * 2 + 0] = z0 - l2;
            out[node * 2 + 1] = z1 - l2;
        }
    }
}

// ---------------------------------------------------------------- launch

extern "C" void kernel_launch(void* const* d_in, const int* in_sizes, int n_in,
                              void* d_out, int out_size, void* d_ws, size_t ws_size,
                              hipStream_t stream) {
    const float* x        = (const float*)d_in[0];
    const int*   ein      = (const int*)d_in[1];
    const int*   eout     = (const int*)d_in[2];
    const float* t        = (const float*)d_in[3];
    const float* te_w[2]  = {(const float*)d_in[4], (const float*)d_in[10]};
    const float* te_b[2]  = {(const float*)d_in[5], (const float*)d_in[11]};
    const float* W1[2]    = {(const float*)d_in[6], (const float*)d_in[12]};
    const float* b1[2]    = {(const float*)d_in[7], (const float*)d_in[13]};
    const float* W2[2]    = {(const float*)d_in[8], (const float*)d_in[14]};
    const float* b2[2]    = {(const float*)d_in[9], (const float*)d_in[15]};
    const float* fc_w     = (const float*)d_in[16];
    const float* fc_b     = (const float*)d_in[17];
    float* out = (float*)d_out;

    char* p = (char*)d_ws;
    auto carve = [&](size_t bytes) {
        void* r = (void*)p;
        p += ((bytes + 255) / 256) * 256;
        return r;
    };
    // big ping-pong buffers: bufA holds bf16-split input (or final fp32 out), bufH fp32 GEMM out
    __hip_bfloat16* bufA = (__hip_bfloat16*)carve((size_t)N_NODES * 1024 * 2);
    float*          bufH = (float*)carve((size_t)N_NODES * D * 4);
    float* z    = (float*)carve((size_t)N_NODES * 2 * 4);
    __hip_bfloat16* W1t[2]; __hip_bfloat16* W2t[2];
    W1t[0] = (__hip_bfloat16*)carve((size_t)D * 1024 * 2);
    W1t[1] = (__hip_bfloat16*)carve((size_t)D * 1024 * 2);
    W2t[0] = (__hip_bfloat16*)carve((size_t)D * 1024 * 2);
    W2t[1] = (__hip_bfloat16*)carve((size_t)D * 1024 * 2);
    int*   cnt[2];   cnt[0]   = (int*)carve(N_NODES * 4);       cnt[1]   = (int*)carve(N_NODES * 4);
    float* dinv[2];  dinv[0]  = (float*)carve(N_NODES * 4);     dinv[1]  = (float*)carve(N_NODES * 4);
    int*   rowp[2];  rowp[0]  = (int*)carve((N_NODES + 1) * 4); rowp[1]  = (int*)carve((N_NODES + 1) * 4);
    int*   fillpos  = (int*)carve(N_NODES * 4);
    int*   esrc[2];  esrc[0]  = (int*)carve(N_EDGES * 4);       esrc[1]  = (int*)carve(N_EDGES * 4);
    float* ecoef[2]; ecoef[0] = (float*)carve(N_EDGES * 4);     ecoef[1] = (float*)carve(N_EDGES * 4);

    const int* edges[2] = {ein, eout};

    int gridE = (N_EDGES + 255) / 256;
    int gridN = (N_NODES + 255) / 256;
    int gridW = (D * D + 255) / 256;
    for (int b = 0; b < 2; ++b) {
        zero_int_kernel<<<gridN, 256, 0, stream>>>(cnt[b], N_NODES);
        deg_kernel<<<gridE, 256, 0, stream>>>(edges[b], cnt[b]);
        dinv_kernel<<<gridN, 256, 0, stream>>>(cnt[b], dinv[b]);
        scan_kernel<<<1, 1024, 0, stream>>>(cnt[b], rowp[b]);
        copy_int_kernel<<<gridN, 256, 0, stream>>>(rowp[b], fillpos, N_NODES);
        fill_kernel<<<gridE, 256, 0, stream>>>(edges[b], dinv[b], fillpos, esrc[b], ecoef[b]);
        split_w_kernel<<<gridW, 256, 0, stream>>>(W1[b], W1t[b]);
        split_w_kernel<<<gridW, 256, 0, stream>>>(W2[b], W2t[b]);
    }

    dim3 gemm_grid(D / 128, (N_NODES + 127) / 128);
    int te_grid = (N_NODES * D + 255) / 256;
    int fin_grid = (N_NODES + 3) / 4;

    for (int b = 0; b < 2; ++b) {
        te_split_kernel<<<te_grid, 256, 0, stream>>>(x, t, te_w[b], te_b[b], bufA);
        gemm_mfma_kernel<<<gemm_grid, 256, 0, stream>>>(bufA, W1t[b], bufH, N_NODES);
        aggregate_kernel<1><<<N_NODES, 256, 0, stream>>>(bufH, rowp[b], esrc[b], ecoef[b],
                                                         dinv[b], b1[b], nullptr, bufA);
        gemm_mfma_kernel<<<gemm_grid, 256, 0, stream>>>(bufA, W2t[b], bufH, N_NODES);
        aggregate_kernel<0><<<N_NODES, 256, 0, stream>>>(bufH, rowp[b], esrc[b], ecoef[b],
                                                         dinv[b], b2[b], (float*)bufA, nullptr);
        final_kernel<<<fin_grid, 256, 0, stream>>>((const float*)bufA, fc_w, fc_b, z, out, b);
    }
}

// Round 3
// 328.720 us; speedup vs baseline: 2.0031x; 1.3773x over previous
//
#include <hip/hip_runtime.h>
#include <hip/hip_bf16.h>
#include <math.h>

#define N_NODES 10000
#define N_EDGES 160000
#define D 512

typedef __attribute__((ext_vector_type(8))) short bf16x8;
typedef __attribute__((ext_vector_type(4))) float f32x4;

__device__ inline void gload_lds16(const void* g, void* l) {
    __builtin_amdgcn_global_load_lds(
        (const __attribute__((address_space(1))) void*)g,
        (__attribute__((address_space(3))) void*)l, 16, 0, 0);
}

__device__ inline float bf2f(short s) {
    return __uint_as_float(((unsigned int)(unsigned short)s) << 16);
}
__device__ inline short f2bf(float f) {
    __hip_bfloat16 h = __float2bfloat16(f);
    return *reinterpret_cast<short*>(&h);
}

// ---------------------------------------------------------------- prep

__global__ void zero2_kernel(int* __restrict__ c0, int* __restrict__ c1) {
    int i = blockIdx.x * blockDim.x + threadIdx.x;
    if (i < N_NODES) c0[i] = 0;
    else if (i < 2 * N_NODES) c1[i - N_NODES] = 0;
}

__global__ void deg2_kernel(const int* __restrict__ ein, const int* __restrict__ eout,
                            int* __restrict__ c0, int* __restrict__ c1) {
    int i = blockIdx.x * blockDim.x + threadIdx.x;
    if (i < N_EDGES) atomicAdd(&c0[ein[N_EDGES + i]], 1);
    else if (i < 2 * N_EDGES) atomicAdd(&c1[eout[N_EDGES + (i - N_EDGES)]], 1);
}

// per-branch block: exclusive scan of cnt -> rowp, plus dinv and fillpos init
__global__ __launch_bounds__(1024) void scan2_kernel(
    const int* __restrict__ c0, const int* __restrict__ c1,
    int* __restrict__ r0, int* __restrict__ r1,
    float* __restrict__ dv0, float* __restrict__ dv1,
    int* __restrict__ f0, int* __restrict__ f1) {
    const int* cnt = blockIdx.x ? c1 : c0;
    int* rowp = blockIdx.x ? r1 : r0;
    float* dinv = blockIdx.x ? dv1 : dv0;
    int* fpos = blockIdx.x ? f1 : f0;
    __shared__ int sm[1024];
    __shared__ int carry;
    if (threadIdx.x == 0) carry = 0;
    __syncthreads();
    for (int base = 0; base < N_NODES; base += 1024) {
        int i = base + threadIdx.x;
        int v = (i < N_NODES) ? cnt[i] : 0;
        if (i < N_NODES) dinv[i] = rsqrtf((float)v + 1.0f);
        sm[threadIdx.x] = v;
        __syncthreads();
        for (int off = 1; off < 1024; off <<= 1) {
            int t = (threadIdx.x >= off) ? sm[threadIdx.x - off] : 0;
            __syncthreads();
            sm[threadIdx.x] += t;
            __syncthreads();
        }
        int incl = sm[threadIdx.x] + carry;
        if (i < N_NODES) {
            rowp[i + 1] = incl;
            fpos[i] = incl - v;
        }
        __syncthreads();
        if (threadIdx.x == 1023) carry = incl;
        __syncthreads();
    }
    if (threadIdx.x == 0) rowp[0] = 0;
}

__global__ void fill2_kernel(const int* __restrict__ ein, const int* __restrict__ eout,
                             const float* __restrict__ dv0, const float* __restrict__ dv1,
                             int* __restrict__ f0, int* __restrict__ f1,
                             int* __restrict__ es0, int* __restrict__ es1,
                             float* __restrict__ ec0, float* __restrict__ ec1) {
    int i = blockIdx.x * blockDim.x + threadIdx.x;
    if (i >= 2 * N_EDGES) return;
    int br = i >= N_EDGES;
    int e = i - br * N_EDGES;
    const int* ei = br ? eout : ein;
    const float* dinv = br ? dv1 : dv0;
    int* fpos = br ? f1 : f0;
    int* esrc = br ? es1 : es0;
    float* ecoef = br ? ec1 : ec0;
    int s = ei[e], d = ei[N_EDGES + e];
    int pos = atomicAdd(&fpos[d], 1);
    esrc[pos] = s;
    ecoef[pos] = dinv[s] * dinv[d];
}

// W[k][n] fp32 -> Bt[n][0..511]=hi, Bt[n][512..1023]=lo ; 4 matrices in one grid
__global__ void split_w4_kernel(const float* __restrict__ w0, const float* __restrict__ w1,
                                const float* __restrict__ w2, const float* __restrict__ w3,
                                __hip_bfloat16* __restrict__ t0, __hip_bfloat16* __restrict__ t1,
                                __hip_bfloat16* __restrict__ t2, __hip_bfloat16* __restrict__ t3) {
    int b = blockIdx.y;
    const float* W = (b == 0) ? w0 : (b == 1) ? w1 : (b == 2) ? w2 : w3;
    __hip_bfloat16* Bt = (b == 0) ? t0 : (b == 1) ? t1 : (b == 2) ? t2 : t3;
    int idx = blockIdx.x * blockDim.x + threadIdx.x;
    if (idx >= D * D) return;
    int k = idx >> 9, n = idx & 511;
    float v = W[k * D + n];
    __hip_bfloat16 h = __float2bfloat16(v);
    float lo = v - __bfloat162float(h);
    Bt[(size_t)n * 1024 + k] = h;
    Bt[(size_t)n * 1024 + 512 + k] = __float2bfloat16(lo);
}

// ------------------------------------------------------------ time encode
// out_bf16[i][j] = bf16(x[i][j] + cos(t[i]*w[j]+b[j]))

__global__ void te_kernel(const float* __restrict__ x, const float* __restrict__ t,
                          const float* __restrict__ w, const float* __restrict__ b,
                          __hip_bfloat16* __restrict__ out) {
    int idx = blockIdx.x * blockDim.x + threadIdx.x;
    if (idx >= N_NODES * 64) return;
    int i = idx >> 6, j0 = (idx & 63) * 8;
    float tv = t[i];
    float4 xa = *(const float4*)&x[(size_t)i * D + j0];
    float4 xb = *(const float4*)&x[(size_t)i * D + j0 + 4];
    float xv[8] = {xa.x, xa.y, xa.z, xa.w, xb.x, xb.y, xb.z, xb.w};
    bf16x8 o;
#pragma unroll
    for (int j = 0; j < 8; ++j)
        o[j] = f2bf(xv[j] + cosf(tv * w[j0 + j] + b[j0 + j]));
    *(bf16x8*)((short*)out + (size_t)i * D + j0) = o;
}

// ---------------------------------------------------------------- MFMA GEMM
// C_bf16[M,512] = A_bf16[M,512] x Bt_split[512][1024]^T, 2-term (B hi+lo).
// 64x128 tile, BK=64, 16 K-steps (t&7 selects A cols; t>=8 uses B lo half).
// LDS rows 128B, XOR-swizzled slots (slot ^ (row&7)).

__global__ __launch_bounds__(256) void gemm_kernel(
    const __hip_bfloat16* __restrict__ A, const __hip_bfloat16* __restrict__ Bt,
    __hip_bfloat16* __restrict__ C, int M) {
    __shared__ __align__(16) char lds[2][24576];  // A 8KB | B 16KB
    const int tid = threadIdx.x, l = tid & 63, wid = tid >> 6;
    const int wm = wid >> 1, wn = wid & 1;
    const int bm = blockIdx.y * 64, bn = blockIdx.x * 128;
    const int rl8 = l >> 3, sslot = (l & 7) ^ rl8;
    const short* Ap = (const short*)A;
    const short* Bp = (const short*)Bt;
    f32x4 acc[2][4] = {};

    auto stage = [&](int cur, int t) {
        int aoff = (t & 7) * 64;
        int boff = (t < 8) ? t * 64 : 512 + (t - 8) * 64;
        char* base = lds[cur];
#pragma unroll
        for (int j = 0; j < 2; ++j) {
            int rowl = wid * 16 + j * 8 + rl8;
            int grow = bm + rowl;
            if (grow > M - 1) grow = M - 1;
            gload_lds16(Ap + (size_t)grow * 512 + aoff + sslot * 8,
                        base + (wid * 16 + j * 8) * 128);
        }
#pragma unroll
        for (int j = 0; j < 4; ++j) {
            int rowl = wid * 32 + j * 8 + rl8;
            gload_lds16(Bp + (size_t)(bn + rowl) * 1024 + boff + sslot * 8,
                        base + 8192 + (wid * 32 + j * 8) * 128);
        }
    };

    auto compute = [&](int cur) {
        const char* baseA = lds[cur];
        const char* baseB = baseA + 8192;
        const int ra = wm * 32 + (l & 15);
        const int rb = wn * 64 + (l & 15);
#pragma unroll
        for (int kk = 0; kk < 2; ++kk) {
            int slot = kk * 4 + (l >> 4);
            bf16x8 af[2], bfr[4];
#pragma unroll
            for (int m = 0; m < 2; ++m) {
                int row = ra + m * 16;
                af[m] = *(const bf16x8*)(baseA + row * 128 + ((slot ^ (row & 7)) * 16));
            }
#pragma unroll
            for (int n = 0; n < 4; ++n) {
                int row = rb + n * 16;
                bfr[n] = *(const bf16x8*)(baseB + row * 128 + ((slot ^ (row & 7)) * 16));
            }
#pragma unroll
            for (int m = 0; m < 2; ++m)
#pragma unroll
                for (int n = 0; n < 4; ++n)
                    acc[m][n] = __builtin_amdgcn_mfma_f32_16x16x32_bf16(
                        af[m], bfr[n], acc[m][n], 0, 0, 0);
        }
    };

    stage(0, 0);
    __syncthreads();
    int cur = 0;
#pragma unroll 1
    for (int t = 0; t < 16; ++t) {
        if (t < 15) stage(cur ^ 1, t + 1);
        compute(cur);
        __syncthreads();
        cur ^= 1;
    }

    const int col0 = bn + wn * 64 + (l & 15);
    const int row0 = bm + wm * 32 + (l >> 4) * 4;
    short* Cp = (short*)C;
#pragma unroll
    for (int m = 0; m < 2; ++m)
#pragma unroll
        for (int n = 0; n < 4; ++n)
#pragma unroll
            for (int r = 0; r < 4; ++r) {
                int row = row0 + m * 16 + r;
                if (row < M) Cp[(size_t)row * D + col0 + n * 16] = f2bf(acc[m][n][r]);
            }
}

// ---------------------------------------------------------------- aggregate
// wave per node: lane covers features lane*8..lane*8+7 (bf16x8 = 16B gather).
// FUSED=0: write bf16 row. FUSED=1: classifier dot + logsoftmax (no h write).
template <int FUSED>
__global__ __launch_bounds__(256) void agg_kernel(
    const __hip_bfloat16* __restrict__ h, const int* __restrict__ rowp,
    const int* __restrict__ esrc, const float* __restrict__ ecoef,
    const float* __restrict__ dinv, const float* __restrict__ bias,
    __hip_bfloat16* __restrict__ outb,
    const float* __restrict__ fcw, const float* __restrict__ fcb,
    float* __restrict__ z, float* __restrict__ out, int branch) {
    int wave = threadIdx.x >> 6, lane = threadIdx.x & 63;
    int node = blockIdx.x * 4 + wave;
    if (node >= N_NODES) return;
    const short* hp = (const short*)h;
    float acc[8] = {};
    int beg = rowp[node], end = rowp[node + 1];
    for (int e = beg; e < end; ++e) {
        int s = esrc[e];
        float c = ecoef[e];
        bf16x8 v = *(const bf16x8*)(hp + (size_t)s * D + lane * 8);
#pragma unroll
        for (int j = 0; j < 8; ++j) acc[j] += c * bf2f(v[j]);
    }
    float dv = dinv[node];
    float selfc = dv * dv;
    {
        bf16x8 v = *(const bf16x8*)(hp + (size_t)node * D + lane * 8);
#pragma unroll
        for (int j = 0; j < 8; ++j) acc[j] += selfc * bf2f(v[j]) + bias[lane * 8 + j];
    }
    if (FUSED == 0) {
        bf16x8 o;
#pragma unroll
        for (int j = 0; j < 8; ++j) o[j] = f2bf(acc[j]);
        *(bf16x8*)((short*)outb + (size_t)node * D + lane * 8) = o;
    } else {
        const float* fw = fcw + (size_t)(branch * D + lane * 8) * 2;
        float z0 = 0.f, z1 = 0.f;
#pragma unroll
        for (int j = 0; j < 8; ++j) {
            z0 += acc[j] * fw[2 * j];
            z1 += acc[j] * fw[2 * j + 1];
        }
#pragma unroll
        for (int off = 32; off; off >>= 1) {
            z0 += __shfl_down(z0, off);
            z1 += __shfl_down(z1, off);
        }
        if (lane == 0) {
            if (branch == 0) {
                z[node * 2 + 0] = z0;
                z[node * 2 + 1] = z1;
            } else {
                z0 += z[node * 2 + 0] + fcb[0];
                z1 += z[node * 2 + 1] + fcb[1];
                float m = fmaxf(z0, z1);
                float l2 = m + logf(expf(z0 - m) + expf(z1 - m));
                out[node * 2 + 0] = z0 - l2;
                out[node * 2 + 1] = z1 - l2;
            }
        }
    }
}

// ---------------------------------------------------------------- launch

extern "C" void kernel_launch(void* const* d_in, const int* in_sizes, int n_in,
                              void* d_out, int out_size, void* d_ws, size_t ws_size,
                              hipStream_t stream) {
    const float* x        = (const float*)d_in[0];
    const int*   ein      = (const int*)d_in[1];
    const int*   eout     = (const int*)d_in[2];
    const float* t        = (const float*)d_in[3];
    const float* te_w[2]  = {(const float*)d_in[4], (const float*)d_in[10]};
    const float* te_b[2]  = {(const float*)d_in[5], (const float*)d_in[11]};
    const float* W1[2]    = {(const float*)d_in[6], (const float*)d_in[12]};
    const float* b1[2]    = {(const float*)d_in[7], (const float*)d_in[13]};
    const float* W2[2]    = {(const float*)d_in[8], (const float*)d_in[14]};
    const float* b2[2]    = {(const float*)d_in[9], (const float*)d_in[15]};
    const float* fc_w     = (const float*)d_in[16];
    const float* fc_b     = (const float*)d_in[17];
    float* out = (float*)d_out;

    char* p = (char*)d_ws;
    auto carve = [&](size_t bytes) {
        void* r = (void*)p;
        p += ((bytes + 255) / 256) * 256;
        return r;
    };
    __hip_bfloat16* actA = (__hip_bfloat16*)carve((size_t)N_NODES * D * 2);  // te out / agg1 out
    __hip_bfloat16* actB = (__hip_bfloat16*)carve((size_t)N_NODES * D * 2);  // gemm out (h1/h2)
    float* z = (float*)carve((size_t)N_NODES * 2 * 4);
    __hip_bfloat16* W1t[2]; __hip_bfloat16* W2t[2];
    W1t[0] = (__hip_bfloat16*)carve((size_t)D * 1024 * 2);
    W1t[1] = (__hip_bfloat16*)carve((size_t)D * 1024 * 2);
    W2t[0] = (__hip_bfloat16*)carve((size_t)D * 1024 * 2);
    W2t[1] = (__hip_bfloat16*)carve((size_t)D * 1024 * 2);
    int*   cnt[2];   cnt[0]   = (int*)carve(N_NODES * 4);       cnt[1]   = (int*)carve(N_NODES * 4);
    float* dinv[2];  dinv[0]  = (float*)carve(N_NODES * 4);     dinv[1]  = (float*)carve(N_NODES * 4);
    int*   rowp[2];  rowp[0]  = (int*)carve((N_NODES + 1) * 4); rowp[1]  = (int*)carve((N_NODES + 1) * 4);
    int*   fpos[2];  fpos[0]  = (int*)carve(N_NODES * 4);       fpos[1]  = (int*)carve(N_NODES * 4);
    int*   esrc[2];  esrc[0]  = (int*)carve(N_EDGES * 4);       esrc[1]  = (int*)carve(N_EDGES * 4);
    float* ecoef[2]; ecoef[0] = (float*)carve(N_EDGES * 4);     ecoef[1] = (float*)carve(N_EDGES * 4);

    // ---- prep (5 launches)
    zero2_kernel<<<(2 * N_NODES + 255) / 256, 256, 0, stream>>>(cnt[0], cnt[1]);
    deg2_kernel<<<(2 * N_EDGES + 255) / 256, 256, 0, stream>>>(ein, eout, cnt[0], cnt[1]);
    scan2_kernel<<<2, 1024, 0, stream>>>(cnt[0], cnt[1], rowp[0], rowp[1],
                                         dinv[0], dinv[1], fpos[0], fpos[1]);
    fill2_kernel<<<(2 * N_EDGES + 255) / 256, 256, 0, stream>>>(
        ein, eout, dinv[0], dinv[1], fpos[0], fpos[1],
        esrc[0], esrc[1], ecoef[0], ecoef[1]);
    split_w4_kernel<<<dim3((D * D + 255) / 256, 4), 256, 0, stream>>>(
        W1[0], W2[0], W1[1], W2[1], W1t[0], W2t[0], W1t[1], W2t[1]);

    // ---- two branches
    dim3 gemm_grid(D / 128, (N_NODES + 63) / 64);
    int te_grid = (N_NODES * 64 + 255) / 256;
    int agg_grid = (N_NODES + 3) / 4;

    for (int b = 0; b < 2; ++b) {
        te_kernel<<<te_grid, 256, 0, stream>>>(x, t, te_w[b], te_b[b], actA);
        gemm_kernel<<<gemm_grid, 256, 0, stream>>>(actA, W1t[b], actB, N_NODES);
        agg_kernel<0><<<agg_grid, 256, 0, stream>>>(actB, rowp[b], esrc[b], ecoef[b],
                                                    dinv[b], b1[b], actA,
                                                    nullptr, nullptr, nullptr, nullptr, b);
        gemm_kernel<<<gemm_grid, 256, 0, stream>>>(actA, W2t[b], actB, N_NODES);
        agg_kernel<1><<<agg_grid, 256, 0, stream>>>(actB, rowp[b], esrc[b], ecoef[b],
                                                    dinv[b], b2[b], nullptr,
                                                    fc_w, fc_b, z, out, b);
    }
}

// Round 4
// 319.012 us; speedup vs baseline: 2.0640x; 1.0304x over previous
//
#include <hip/hip_runtime.h>
#include <hip/hip_bf16.h>
#include <math.h>

#define N_NODES 10000
#define N_EDGES 160000
#define D 512

typedef __attribute__((ext_vector_type(8))) short bf16x8;
typedef __attribute__((ext_vector_type(4))) short bf16x4;
typedef __attribute__((ext_vector_type(4))) float f32x4;

__device__ inline void gload_lds16(const void* g, void* l) {
    __builtin_amdgcn_global_load_lds(
        (const __attribute__((address_space(1))) void*)g,
        (__attribute__((address_space(3))) void*)l, 16, 0, 0);
}

__device__ inline float bf2f(short s) {
    return __uint_as_float(((unsigned int)(unsigned short)s) << 16);
}
__device__ inline short f2bf(float f) {
    __hip_bfloat16 h = __float2bfloat16(f);
    return *reinterpret_cast<short*>(&h);
}

// ---------------------------------------------------------------- prep

__global__ void zero2_kernel(int* __restrict__ c0, int* __restrict__ c1) {
    int i = blockIdx.x * blockDim.x + threadIdx.x;
    if (i < N_NODES) c0[i] = 0;
    else if (i < 2 * N_NODES) c1[i - N_NODES] = 0;
}

__global__ void deg2_kernel(const int* __restrict__ ein, const int* __restrict__ eout,
                            int* __restrict__ c0, int* __restrict__ c1) {
    int i = blockIdx.x * blockDim.x + threadIdx.x;
    if (i < N_EDGES) atomicAdd(&c0[ein[N_EDGES + i]], 1);
    else if (i < 2 * N_EDGES) atomicAdd(&c1[eout[N_EDGES + (i - N_EDGES)]], 1);
}

// blockIdx.x = branch. 10 elems/thread local scan + one block scan.
__global__ __launch_bounds__(1024) void scan2_kernel(
    const int* __restrict__ c0, const int* __restrict__ c1,
    int* __restrict__ r0, int* __restrict__ r1,
    float* __restrict__ dv0, float* __restrict__ dv1,
    int* __restrict__ f0, int* __restrict__ f1) {
    const int* cnt = blockIdx.x ? c1 : c0;
    int* rowp = blockIdx.x ? r1 : r0;
    float* dinv = blockIdx.x ? dv1 : dv0;
    int* fpos = blockIdx.x ? f1 : f0;
    __shared__ int sm[1024];
    const int t = threadIdx.x;
    const int base = t * 10;
    int local[10];
    int tsum = 0;
#pragma unroll
    for (int j = 0; j < 10; ++j) {
        int i = base + j;
        int v = (i < N_NODES) ? cnt[i] : 0;
        local[j] = tsum;
        tsum += v;
    }
    sm[t] = tsum;
    __syncthreads();
    for (int off = 1; off < 1024; off <<= 1) {
        int tv = (t >= off) ? sm[t - off] : 0;
        __syncthreads();
        sm[t] += tv;
        __syncthreads();
    }
    int carry = t ? sm[t - 1] : 0;
#pragma unroll
    for (int j = 0; j < 10; ++j) {
        int i = base + j;
        if (i < N_NODES) {
            int excl = carry + local[j];
            rowp[i] = excl;
            fpos[i] = excl;
            dinv[i] = rsqrtf((float)cnt[i] + 1.0f);
        }
    }
    if (t == 1023) rowp[N_NODES] = sm[1023];
}

__global__ void fill2_kernel(const int* __restrict__ ein, const int* __restrict__ eout,
                             const float* __restrict__ dv0, const float* __restrict__ dv1,
                             int* __restrict__ f0, int* __restrict__ f1,
                             int* __restrict__ es0, int* __restrict__ es1,
                             float* __restrict__ ec0, float* __restrict__ ec1) {
    int i = blockIdx.x * blockDim.x + threadIdx.x;
    if (i >= 2 * N_EDGES) return;
    int br = i >= N_EDGES;
    int e = i - br * N_EDGES;
    const int* ei = br ? eout : ein;
    const float* dinv = br ? dv1 : dv0;
    int* fpos = br ? f1 : f0;
    int* esrc = br ? es1 : es0;
    float* ecoef = br ? ec1 : ec0;
    int s = ei[e], d = ei[N_EDGES + e];
    int pos = atomicAdd(&fpos[d], 1);
    esrc[pos] = s;
    ecoef[pos] = dinv[s] * dinv[d];
}

// W[k][n] fp32 -> Bt[n][0..511]=hi, Bt[n][512..1023]=lo ; 4 matrices
__global__ void split_w4_kernel(const float* __restrict__ w0, const float* __restrict__ w1,
                                const float* __restrict__ w2, const float* __restrict__ w3,
                                __hip_bfloat16* __restrict__ t0, __hip_bfloat16* __restrict__ t1,
                                __hip_bfloat16* __restrict__ t2, __hip_bfloat16* __restrict__ t3) {
    int b = blockIdx.y;
    const float* W = (b == 0) ? w0 : (b == 1) ? w1 : (b == 2) ? w2 : w3;
    __hip_bfloat16* Bt = (b == 0) ? t0 : (b == 1) ? t1 : (b == 2) ? t2 : t3;
    int idx = blockIdx.x * blockDim.x + threadIdx.x;
    if (idx >= D * D) return;
    int k = idx >> 9, n = idx & 511;
    float v = W[k * D + n];
    __hip_bfloat16 h = __float2bfloat16(v);
    float lo = v - __bfloat162float(h);
    Bt[(size_t)n * 1024 + k] = h;
    Bt[(size_t)n * 1024 + 512 + k] = __float2bfloat16(lo);
}

// ------------------------------------------------------------ time encode
// both branches in one grid; out bf16

__global__ void te2_kernel(const float* __restrict__ x, const float* __restrict__ t,
                           const float* __restrict__ w0, const float* __restrict__ b0,
                           const float* __restrict__ w1, const float* __restrict__ b1,
                           __hip_bfloat16* __restrict__ o0, __hip_bfloat16* __restrict__ o1) {
    int idx = blockIdx.x * blockDim.x + threadIdx.x;
    if (idx >= 2 * N_NODES * 64) return;
    int br = idx >= N_NODES * 64;
    int r = idx - br * N_NODES * 64;
    const float* w = br ? w1 : w0;
    const float* b = br ? b1 : b0;
    short* out = (short*)(br ? o1 : o0);
    int i = r >> 6, j0 = (r & 63) * 8;
    float tv = t[i];
    float4 xa = *(const float4*)&x[(size_t)i * D + j0];
    float4 xb = *(const float4*)&x[(size_t)i * D + j0 + 4];
    float xv[8] = {xa.x, xa.y, xa.z, xa.w, xb.x, xb.y, xb.z, xb.w};
    bf16x8 o;
#pragma unroll
    for (int j = 0; j < 8; ++j)
        o[j] = f2bf(xv[j] + cosf(tv * w[j0 + j] + b[j0 + j]));
    *(bf16x8*)(out + (size_t)i * D + j0) = o;
}

// ---------------------------------------------------------------- MFMA GEMM
// C_bf16[M,512] = A_bf16[M,512] x Bt_split[512][1024]^T, 2-term (B hi+lo).
// 64x128 tile, BK=64, 16 K-steps. blockIdx.z = branch.
// LDS rows 128B, XOR-swizzled slots (slot ^ (row&7)).

__global__ __launch_bounds__(256) void gemm_kernel(
    const __hip_bfloat16* __restrict__ A0, const __hip_bfloat16* __restrict__ A1,
    const __hip_bfloat16* __restrict__ B0, const __hip_bfloat16* __restrict__ B1,
    __hip_bfloat16* __restrict__ C0, __hip_bfloat16* __restrict__ C1, int M) {
    __shared__ __align__(16) char lds[2][24576];  // A 8KB | B 16KB
    const int tid = threadIdx.x, l = tid & 63, wid = tid >> 6;
    const int wm = wid >> 1, wn = wid & 1;
    const int bm = blockIdx.y * 64, bn = blockIdx.x * 128;
    const int bz = blockIdx.z;
    const int rl8 = l >> 3, sslot = (l & 7) ^ rl8;
    const short* Ap = (const short*)(bz ? A1 : A0);
    const short* Bp = (const short*)(bz ? B1 : B0);
    short* Cp = (short*)(bz ? C1 : C0);
    f32x4 acc[2][4] = {};

    auto stage = [&](int cur, int t) {
        int aoff = (t & 7) * 64;
        int boff = (t < 8) ? t * 64 : 512 + (t - 8) * 64;
        char* base = lds[cur];
#pragma unroll
        for (int j = 0; j < 2; ++j) {
            int rowl = wid * 16 + j * 8 + rl8;
            int grow = bm + rowl;
            if (grow > M - 1) grow = M - 1;
            gload_lds16(Ap + (size_t)grow * 512 + aoff + sslot * 8,
                        base + (wid * 16 + j * 8) * 128);
        }
#pragma unroll
        for (int j = 0; j < 4; ++j) {
            int rowl = wid * 32 + j * 8 + rl8;
            gload_lds16(Bp + (size_t)(bn + rowl) * 1024 + boff + sslot * 8,
                        base + 8192 + (wid * 32 + j * 8) * 128);
        }
    };

    auto compute = [&](int cur) {
        const char* baseA = lds[cur];
        const char* baseB = baseA + 8192;
        const int ra = wm * 32 + (l & 15);
        const int rb = wn * 64 + (l & 15);
#pragma unroll
        for (int kk = 0; kk < 2; ++kk) {
            int slot = kk * 4 + (l >> 4);
            bf16x8 af[2], bfr[4];
#pragma unroll
            for (int m = 0; m < 2; ++m) {
                int row = ra + m * 16;
                af[m] = *(const bf16x8*)(baseA + row * 128 + ((slot ^ (row & 7)) * 16));
            }
#pragma unroll
            for (int n = 0; n < 4; ++n) {
                int row = rb + n * 16;
                bfr[n] = *(const bf16x8*)(baseB + row * 128 + ((slot ^ (row & 7)) * 16));
            }
#pragma unroll
            for (int m = 0; m < 2; ++m)
#pragma unroll
                for (int n = 0; n < 4; ++n)
                    acc[m][n] = __builtin_amdgcn_mfma_f32_16x16x32_bf16(
                        af[m], bfr[n], acc[m][n], 0, 0, 0);
        }
    };

    stage(0, 0);
    __syncthreads();
    int cur = 0;
#pragma unroll 1
    for (int t = 0; t < 16; ++t) {
        if (t < 15) stage(cur ^ 1, t + 1);
        compute(cur);
        __syncthreads();
        cur ^= 1;
    }

    const int col0 = bn + wn * 64 + (l & 15);
    const int row0 = bm + wm * 32 + (l >> 4) * 4;
#pragma unroll
    for (int m = 0; m < 2; ++m)
#pragma unroll
        for (int n = 0; n < 4; ++n)
#pragma unroll
            for (int r = 0; r < 4; ++r) {
                int row = row0 + m * 16 + r;
                if (row < M) Cp[(size_t)row * D + col0 + n * 16] = f2bf(acc[m][n][r]);
            }
}

// ---------------------------------------------------------------- aggregate 1
// 2 waves per node per branch; lane covers 4 features (8B gather). bf16 out.

__global__ __launch_bounds__(512) void agg1_kernel(
    const __hip_bfloat16* __restrict__ h0, const __hip_bfloat16* __restrict__ h1,
    const int* __restrict__ rp0, const int* __restrict__ rp1,
    const int* __restrict__ es0, const int* __restrict__ es1,
    const float* __restrict__ ec0, const float* __restrict__ ec1,
    const float* __restrict__ dv0, const float* __restrict__ dv1,
    const float* __restrict__ bs0, const float* __restrict__ bs1,
    __hip_bfloat16* __restrict__ o0, __hip_bfloat16* __restrict__ o1) {
    int gid = blockIdx.x * 8 + (threadIdx.x >> 6);
    if (gid >= 4 * N_NODES) return;
    int lane = threadIdx.x & 63;
    int branch = gid >= 2 * N_NODES;
    int r = gid - branch * 2 * N_NODES;
    int node = r >> 1;
    int f0 = (r & 1) * 256 + lane * 4;
    const short* hp = (const short*)(branch ? h1 : h0);
    const int* rowp = branch ? rp1 : rp0;
    const int* esrc = branch ? es1 : es0;
    const float* ecoef = branch ? ec1 : ec0;
    const float* dinv = branch ? dv1 : dv0;
    const float* bias = branch ? bs1 : bs0;
    short* op = (short*)(branch ? o1 : o0);

    float acc[4] = {};
    int beg = rowp[node], end = rowp[node + 1];
    for (int e = beg; e < end; ++e) {
        int s = esrc[e];
        float c = ecoef[e];
        bf16x4 v = *(const bf16x4*)(hp + (size_t)s * D + f0);
#pragma unroll
        for (int j = 0; j < 4; ++j) acc[j] += c * bf2f(v[j]);
    }
    float dv = dinv[node];
    float selfc = dv * dv;
    {
        bf16x4 v = *(const bf16x4*)(hp + (size_t)node * D + f0);
#pragma unroll
        for (int j = 0; j < 4; ++j) acc[j] += selfc * bf2f(v[j]) + bias[f0 + j];
    }
    bf16x4 o;
#pragma unroll
    for (int j = 0; j < 4; ++j) o[j] = f2bf(acc[j]);
    *(bf16x4*)(op + (size_t)node * D + f0) = o;
}

// ------------------------------------------- aggregate 2 + classifier + lsm
// 1 wave per node; gathers both branches, 1024-dot in-register, writes out[2].

__global__ __launch_bounds__(256) void agg2_final_kernel(
    const __hip_bfloat16* __restrict__ h0, const __hip_bfloat16* __restrict__ h1,
    const int* __restrict__ rp0, const int* __restrict__ rp1,
    const int* __restrict__ es0, const int* __restrict__ es1,
    const float* __restrict__ ec0, const float* __restrict__ ec1,
    const float* __restrict__ dv0, const float* __restrict__ dv1,
    const float* __restrict__ bs0, const float* __restrict__ bs1,
    const float* __restrict__ fcw, const float* __restrict__ fcb,
    float* __restrict__ out) {
    int node = blockIdx.x * 4 + (threadIdx.x >> 6);
    if (node >= N_NODES) return;
    int lane = threadIdx.x & 63;
    float z0 = 0.f, z1 = 0.f;

#pragma unroll
    for (int branch = 0; branch < 2; ++branch) {
        const short* hp = (const short*)(branch ? h1 : h0);
        const int* rowp = branch ? rp1 : rp0;
        const int* esrc = branch ? es1 : es0;
        const float* ecoef = branch ? ec1 : ec0;
        const float* dinv = branch ? dv1 : dv0;
        const float* bias = branch ? bs1 : bs0;
        float acc[8] = {};
        int beg = rowp[node], end = rowp[node + 1];
        for (int e = beg; e < end; ++e) {
            int s = esrc[e];
            float c = ecoef[e];
            bf16x8 v = *(const bf16x8*)(hp + (size_t)s * D + lane * 8);
#pragma unroll
            for (int j = 0; j < 8; ++j) acc[j] += c * bf2f(v[j]);
        }
        float dv = dinv[node];
        float selfc = dv * dv;
        bf16x8 v = *(const bf16x8*)(hp + (size_t)node * D + lane * 8);
        const float* fw = fcw + (size_t)(branch * D + lane * 8) * 2;
#pragma unroll
        for (int j = 0; j < 8; ++j) {
            float a = acc[j] + selfc * bf2f(v[j]) + bias[lane * 8 + j];
            z0 += a * fw[2 * j];
            z1 += a * fw[2 * j + 1];
        }
    }
#pragma unroll
    for (int off = 32; off; off >>= 1) {
        z0 += __shfl_down(z0, off);
        z1 += __shfl_down(z1, off);
    }
    if (lane == 0) {
        z0 += fcb[0];
        z1 += fcb[1];
        float m = fmaxf(z0, z1);
        float l2 = m + logf(expf(z0 - m) + expf(z1 - m));
        out[node * 2 + 0] = z0 - l2;
        out[node * 2 + 1] = z1 - l2;
    }
}

// ---------------------------------------------------------------- launch

extern "C" void kernel_launch(void* const* d_in, const int* in_sizes, int n_in,
                              void* d_out, int out_size, void* d_ws, size_t ws_size,
                              hipStream_t stream) {
    const float* x        = (const float*)d_in[0];
    const int*   ein      = (const int*)d_in[1];
    const int*   eout     = (const int*)d_in[2];
    const float* t        = (const float*)d_in[3];
    const float* te_w[2]  = {(const float*)d_in[4], (const float*)d_in[10]};
    const float* te_b[2]  = {(const float*)d_in[5], (const float*)d_in[11]};
    const float* W1[2]    = {(const float*)d_in[6], (const float*)d_in[12]};
    const float* b1[2]    = {(const float*)d_in[7], (const float*)d_in[13]};
    const float* W2[2]    = {(const float*)d_in[8], (const float*)d_in[14]};
    const float* b2[2]    = {(const float*)d_in[9], (const float*)d_in[15]};
    const float* fc_w     = (const float*)d_in[16];
    const float* fc_b     = (const float*)d_in[17];
    float* out = (float*)d_out;

    char* p = (char*)d_ws;
    auto carve = [&](size_t bytes) {
        void* r = (void*)p;
        p += ((bytes + 255) / 256) * 256;
        return r;
    };
    __hip_bfloat16* actA[2];  // te out / agg1 out
    __hip_bfloat16* actB[2];  // gemm out
    actA[0] = (__hip_bfloat16*)carve((size_t)N_NODES * D * 2);
    actA[1] = (__hip_bfloat16*)carve((size_t)N_NODES * D * 2);
    actB[0] = (__hip_bfloat16*)carve((size_t)N_NODES * D * 2);
    actB[1] = (__hip_bfloat16*)carve((size_t)N_NODES * D * 2);
    __hip_bfloat16* W1t[2]; __hip_bfloat16* W2t[2];
    W1t[0] = (__hip_bfloat16*)carve((size_t)D * 1024 * 2);
    W1t[1] = (__hip_bfloat16*)carve((size_t)D * 1024 * 2);
    W2t[0] = (__hip_bfloat16*)carve((size_t)D * 1024 * 2);
    W2t[1] = (__hip_bfloat16*)carve((size_t)D * 1024 * 2);
    int*   cnt[2];   cnt[0]   = (int*)carve(N_NODES * 4);       cnt[1]   = (int*)carve(N_NODES * 4);
    float* dinv[2];  dinv[0]  = (float*)carve(N_NODES * 4);     dinv[1]  = (float*)carve(N_NODES * 4);
    int*   rowp[2];  rowp[0]  = (int*)carve((N_NODES + 1) * 4); rowp[1]  = (int*)carve((N_NODES + 1) * 4);
    int*   fpos[2];  fpos[0]  = (int*)carve(N_NODES * 4);       fpos[1]  = (int*)carve(N_NODES * 4);
    int*   esrc[2];  esrc[0]  = (int*)carve(N_EDGES * 4);       esrc[1]  = (int*)carve(N_EDGES * 4);
    float* ecoef[2]; ecoef[0] = (float*)carve(N_EDGES * 4);     ecoef[1] = (float*)carve(N_EDGES * 4);

    // ---- prep
    zero2_kernel<<<(2 * N_NODES + 255) / 256, 256, 0, stream>>>(cnt[0], cnt[1]);
    deg2_kernel<<<(2 * N_EDGES + 255) / 256, 256, 0, stream>>>(ein, eout, cnt[0], cnt[1]);
    scan2_kernel<<<2, 1024, 0, stream>>>(cnt[0], cnt[1], rowp[0], rowp[1],
                                         dinv[0], dinv[1], fpos[0], fpos[1]);
    fill2_kernel<<<(2 * N_EDGES + 255) / 256, 256, 0, stream>>>(
        ein, eout, dinv[0], dinv[1], fpos[0], fpos[1],
        esrc[0], esrc[1], ecoef[0], ecoef[1]);
    split_w4_kernel<<<dim3((D * D + 255) / 256, 4), 256, 0, stream>>>(
        W1[0], W2[0], W1[1], W2[1], W1t[0], W2t[0], W1t[1], W2t[1]);

    // ---- fused-branch pipeline
    dim3 gemm_grid(D / 128, (N_NODES + 63) / 64, 2);

    te2_kernel<<<(2 * N_NODES * 64 + 255) / 256, 256, 0, stream>>>(
        x, t, te_w[0], te_b[0], te_w[1], te_b[1], actA[0], actA[1]);
    gemm_kernel<<<gemm_grid, 256, 0, stream>>>(actA[0], actA[1], W1t[0], W1t[1],
                                               actB[0], actB[1], N_NODES);
    agg1_kernel<<<(4 * N_NODES + 7) / 8, 512, 0, stream>>>(
        actB[0], actB[1], rowp[0], rowp[1], esrc[0], esrc[1], ecoef[0], ecoef[1],
        dinv[0], dinv[1], b1[0], b1[1], actA[0], actA[1]);
    gemm_kernel<<<gemm_grid, 256, 0, stream>>>(actA[0], actA[1], W2t[0], W2t[1],
                                               actB[0], actB[1], N_NODES);
    agg2_final_kernel<<<(N_NODES + 3) / 4, 256, 0, stream>>>(
        actB[0], actB[1], rowp[0], rowp[1], esrc[0], esrc[1], ecoef[0], ecoef[1],
        dinv[0], dinv[1], b2[0], b2[1], fc_w, fc_b, out);
}